// Round 2
// baseline (536.561 us; speedup 1.0000x reference)
//
#include <hip/hip_runtime.h>
#include <stdint.h>

#define M_DIM 8192
#define N_DIM 4096
#define K_DIM 4096
#define NUM_VQ (N_DIM * K_DIM / 8)     // 2,097,152 VQ blocks
#define NUM_X  (M_DIM * K_DIM)         // 33,554,432 x elements

typedef __attribute__((ext_vector_type(4))) float f32x4;
typedef __attribute__((ext_vector_type(8))) short bf16x8;
typedef unsigned short u16;

__device__ inline unsigned short f2bf(float f) {
    union { float f; unsigned int i; } v; v.f = f;
    unsigned int x = v.i;
    return (unsigned short)((x + 0x7FFFu + ((x >> 16) & 1u)) >> 16);  // RNE
}

// ---------------------------------------------------------------------------
// Probe: labels int64 (odd int32 words all zero) vs int32.
// ---------------------------------------------------------------------------
__global__ void detect_i64(const int* __restrict__ labels, int* __restrict__ flag) {
    if (threadIdx.x == 0) {
        int is64 = 1;
        for (int i = 1; i < 128; i += 2)
            if (labels[i] != 0) { is64 = 0; break; }
        *flag = is64;
    }
}

// ---------------------------------------------------------------------------
// x fp32 -> bf16.  8 elements / thread: 2 x float4 load, 1 x 16B store.
// ---------------------------------------------------------------------------
__global__ void convert_x(const float* __restrict__ x, u16* __restrict__ xb) {
    int i = blockIdx.x * blockDim.x + threadIdx.x;   // 8-element group
    f32x4 a = ((const f32x4*)x)[2 * i];
    f32x4 b = ((const f32x4*)x)[2 * i + 1];
    bf16x8 o;
#pragma unroll
    for (int j = 0; j < 4; ++j) { o[j] = (short)f2bf(a[j]); o[4 + j] = (short)f2bf(b[j]); }
    ((bf16x8*)xb)[i] = o;
}

// ---------------------------------------------------------------------------
// VQ decompress + scale fold: Ws[n][k] = bf16(centroids[lab][k%8] * scale[k]).
// centroids/scale fp32.  One thread per 8-wide VQ block.
// ---------------------------------------------------------------------------
__global__ void decompress(const int* __restrict__ labels,
                           const float* __restrict__ centroids,
                           const float* __restrict__ scale,
                           u16* __restrict__ Ws,
                           const int* __restrict__ flag) {
    int i = blockIdx.x * blockDim.x + threadIdx.x;
    int lab = (*flag) ? labels[2 * i] : labels[i];
    int kb = i & 511;                                // k-block within row
    f32x4 c0 = ((const f32x4*)centroids)[2 * lab];
    f32x4 c1 = ((const f32x4*)centroids)[2 * lab + 1];
    f32x4 s0 = ((const f32x4*)scale)[2 * kb];
    f32x4 s1 = ((const f32x4*)scale)[2 * kb + 1];
    bf16x8 o;
#pragma unroll
    for (int j = 0; j < 4; ++j) {
        o[j]     = (short)f2bf(c0[j] * s0[j]);
        o[4 + j] = (short)f2bf(c1[j] * s1[j]);
    }
    ((bf16x8*)Ws)[i] = o;
}

// ---------------------------------------------------------------------------
// bf16 GEMM, C = A @ Ws^T + bias (fp32 out).  A: [M][K] bf16, Ws: [N][K] bf16.
// m97 structure: 128x128 tile, BK=32, 4 waves x (4x4) mfma_f32_16x16x32_bf16,
// global_load_lds width=16 staging for both operands.
// ---------------------------------------------------------------------------
__global__ __launch_bounds__(256)
void gemm_bias(const u16* __restrict__ A, const u16* __restrict__ B,
               const float* __restrict__ bias, float* __restrict__ C) {
    __shared__ u16 ldsA[128 * 32];
    __shared__ u16 ldsB[128 * 32];

    const int tid  = threadIdx.x;
    const int wave = tid >> 6;
    const int lane = tid & 63;
    const int bm = blockIdx.y * 128;
    const int bn = blockIdx.x * 128;

    const int srow = wave * 32 + (lane >> 2);
    const int scol = (lane & 3) * 8;
    const u16* gA = A + (size_t)(bm + srow) * K_DIM + scol;
    const u16* gB = B + (size_t)(bn + srow) * K_DIM + scol;
    u16* lA = ldsA + wave * 1024;    // HW writes base + lane*16B = lane*8 u16
    u16* lB = ldsB + wave * 1024;    //   == (lane>>2)*32 + (lane&3)*8  (row-major 32)

    const int wm = (wave >> 1) * 64;
    const int wn = (wave & 1) * 64;
    const int fm = lane & 15;
    const int fk = (lane >> 4) * 8;

    f32x4 acc[4][4];
#pragma unroll
    for (int i = 0; i < 4; ++i)
#pragma unroll
        for (int j = 0; j < 4; ++j)
            acc[i][j] = (f32x4){0.f, 0.f, 0.f, 0.f};

    for (int kt = 0; kt < K_DIM / 32; ++kt) {
        __builtin_amdgcn_global_load_lds(
            (const __attribute__((address_space(1))) void*)gA,
            (__attribute__((address_space(3))) void*)lA, 16, 0, 0);
        __builtin_amdgcn_global_load_lds(
            (const __attribute__((address_space(1))) void*)(gA + 16 * K_DIM),
            (__attribute__((address_space(3))) void*)(lA + 512), 16, 0, 0);
        __builtin_amdgcn_global_load_lds(
            (const __attribute__((address_space(1))) void*)gB,
            (__attribute__((address_space(3))) void*)lB, 16, 0, 0);
        __builtin_amdgcn_global_load_lds(
            (const __attribute__((address_space(1))) void*)(gB + 16 * K_DIM),
            (__attribute__((address_space(3))) void*)(lB + 512), 16, 0, 0);
        gA += 32;
        gB += 32;
        __syncthreads();

        bf16x8 af[4], bfr[4];
#pragma unroll
        for (int i = 0; i < 4; ++i)
            af[i] = *(const bf16x8*)&ldsA[(wm + i * 16 + fm) * 32 + fk];
#pragma unroll
        for (int j = 0; j < 4; ++j)
            bfr[j] = *(const bf16x8*)&ldsB[(wn + j * 16 + fm) * 32 + fk];

#pragma unroll
        for (int i = 0; i < 4; ++i)
#pragma unroll
            for (int j = 0; j < 4; ++j)
                acc[i][j] = __builtin_amdgcn_mfma_f32_16x16x32_bf16(
                    af[i], bfr[j], acc[i][j], 0, 0, 0);
        __syncthreads();
    }

    float biasv[4];
#pragma unroll
    for (int j = 0; j < 4; ++j)
        biasv[j] = bias[bn + wn + j * 16 + (lane & 15)];

    const int crow0 = bm + wm + (lane >> 4) * 4;
    const int ccol0 = bn + wn + (lane & 15);
#pragma unroll
    for (int i = 0; i < 4; ++i)
#pragma unroll
        for (int r = 0; r < 4; ++r) {
            size_t rowoff = (size_t)(crow0 + i * 16 + r) * N_DIM;
#pragma unroll
            for (int j = 0; j < 4; ++j)
                C[rowoff + ccol0 + j * 16] = acc[i][j][r] + biasv[j];
        }
}

// ---------------------------------------------------------------------------
// Tier-B fallback (workspace too small for converted X): A staged via fp32
// global loads + in-register bf16 convert + ds_write; B via global_load_lds.
// ---------------------------------------------------------------------------
__global__ __launch_bounds__(256)
void gemm_bias_cvtA(const float* __restrict__ A32, const u16* __restrict__ B,
                    const float* __restrict__ bias, float* __restrict__ C) {
    __shared__ u16 ldsA[128 * 32];
    __shared__ u16 ldsB[128 * 32];

    const int tid  = threadIdx.x;
    const int wave = tid >> 6;
    const int lane = tid & 63;
    const int bm = blockIdx.y * 128;
    const int bn = blockIdx.x * 128;

    const int srow = wave * 32 + (lane >> 2);
    const int scol = (lane & 3) * 8;
    const float* gA = A32 + (size_t)(bm + srow) * K_DIM + scol;
    const u16*   gB = B   + (size_t)(bn + srow) * K_DIM + scol;
    u16* lA = ldsA + wave * 1024;
    u16* lB = ldsB + wave * 1024;
    const int ldst = lane * 8;      // matches HW lane*16B mapping of tier A

    const int wm = (wave >> 1) * 64;
    const int wn = (wave & 1) * 64;
    const int fm = lane & 15;
    const int fk = (lane >> 4) * 8;

    f32x4 acc[4][4];
#pragma unroll
    for (int i = 0; i < 4; ++i)
#pragma unroll
        for (int j = 0; j < 4; ++j)
            acc[i][j] = (f32x4){0.f, 0.f, 0.f, 0.f};

    for (int kt = 0; kt < K_DIM / 32; ++kt) {
        f32x4 a0 = *(const f32x4*)gA;
        f32x4 a1 = *(const f32x4*)(gA + 4);
        f32x4 a2 = *(const f32x4*)(gA + 16 * K_DIM);
        f32x4 a3 = *(const f32x4*)(gA + 16 * K_DIM + 4);
        __builtin_amdgcn_global_load_lds(
            (const __attribute__((address_space(1))) void*)gB,
            (__attribute__((address_space(3))) void*)lB, 16, 0, 0);
        __builtin_amdgcn_global_load_lds(
            (const __attribute__((address_space(1))) void*)(gB + 16 * K_DIM),
            (__attribute__((address_space(3))) void*)(lB + 512), 16, 0, 0);
        bf16x8 p0, p1;
#pragma unroll
        for (int j = 0; j < 4; ++j) {
            p0[j] = (short)f2bf(a0[j]); p0[4 + j] = (short)f2bf(a1[j]);
            p1[j] = (short)f2bf(a2[j]); p1[4 + j] = (short)f2bf(a3[j]);
        }
        *(bf16x8*)&lA[ldst]       = p0;
        *(bf16x8*)&lA[ldst + 512] = p1;
        gA += 32;
        gB += 32;
        __syncthreads();

        bf16x8 af[4], bfr[4];
#pragma unroll
        for (int i = 0; i < 4; ++i)
            af[i] = *(const bf16x8*)&ldsA[(wm + i * 16 + fm) * 32 + fk];
#pragma unroll
        for (int j = 0; j < 4; ++j)
            bfr[j] = *(const bf16x8*)&ldsB[(wn + j * 16 + fm) * 32 + fk];

#pragma unroll
        for (int i = 0; i < 4; ++i)
#pragma unroll
            for (int j = 0; j < 4; ++j)
                acc[i][j] = __builtin_amdgcn_mfma_f32_16x16x32_bf16(
                    af[i], bfr[j], acc[i][j], 0, 0, 0);
        __syncthreads();
    }

    float biasv[4];
#pragma unroll
    for (int j = 0; j < 4; ++j)
        biasv[j] = bias[bn + wn + j * 16 + (lane & 15)];

    const int crow0 = bm + wm + (lane >> 4) * 4;
    const int ccol0 = bn + wn + (lane & 15);
#pragma unroll
    for (int i = 0; i < 4; ++i)
#pragma unroll
        for (int r = 0; r < 4; ++r) {
            size_t rowoff = (size_t)(crow0 + i * 16 + r) * N_DIM;
#pragma unroll
            for (int j = 0; j < 4; ++j)
                C[rowoff + ccol0 + j * 16] = acc[i][j][r] + biasv[j];
        }
}

extern "C" void kernel_launch(void* const* d_in, const int* in_sizes, int n_in,
                              void* d_out, int out_size, void* d_ws, size_t ws_size,
                              hipStream_t stream) {
    const float* x         = (const float*)d_in[0];   // [4,2048,4096] fp32
    const float* centroids = (const float*)d_in[1];   // [256,8] fp32
    const int*   labels    = (const int*)d_in[2];     // [2M] int32/64
    const float* scale     = (const float*)d_in[3];   // [4096] fp32
    const float* bias      = (const float*)d_in[4];   // [4096] fp32
    float* out             = (float*)d_out;           // [4,2048,4096] fp32

    int* flag = (int*)d_ws;
    u16* Ws   = (u16*)((char*)d_ws + 256);                      // 32 MB
    u16* Xb   = (u16*)((char*)d_ws + 256 + (size_t)NUM_VQ * 16); // 64 MB

    const size_t need_full = 256 + (size_t)NUM_VQ * 16 + (size_t)NUM_X * 2;
    const size_t need_ws   = 256 + (size_t)NUM_VQ * 16;

    detect_i64<<<1, 64, 0, stream>>>(labels, flag);
    decompress<<<NUM_VQ / 256, 256, 0, stream>>>(labels, centroids, scale, Ws, flag);

    dim3 grid(N_DIM / 128, M_DIM / 128);
    if (ws_size >= need_full) {
        convert_x<<<NUM_X / 8 / 256, 256, 0, stream>>>(x, Xb);
        gemm_bias<<<grid, 256, 0, stream>>>(Xb, Ws, bias, out);
    } else if (ws_size >= need_ws) {
        gemm_bias_cvtA<<<grid, 256, 0, stream>>>(x, Ws, bias, out);
    }
    // (ws_size below need_ws is not expected; harness workspace is generous)
}